// Round 1
// baseline (2362.125 us; speedup 1.0000x reference)
//
#include <hip/hip_runtime.h>

#define CIN 3
#define C1_ 32
#define C2_ 64
#define FC1N 256
#define NCLS 10

// ---------------------------------------------------------------------------
// Fused front: locally-connected 3x3 (unshared weights) + ReLU + maxpool2
//              + conv3x3 SAME + bias + ReLU + maxpool2
// One block per batch image, 256 threads.
//   LDS: x image (12 KB) + pooled LC output y1 (32x16, row stride 24 -> 49 KB)
// ---------------------------------------------------------------------------
__global__ __launch_bounds__(256) void k_front(
    const float* __restrict__ x,      // (B,3,32,32)
    const float* __restrict__ w_lc,   // (32,3,9,32,32)
    const float* __restrict__ b_lc,   // (32,32,32)
    const float* __restrict__ w_conv, // (64,32,3,3)
    const float* __restrict__ b_conv, // (64,)
    float* __restrict__ p2)           // (B,64,8,8) flattened (B,4096)
{
    __shared__ float xs[CIN][32][32];   // 12 KB
    __shared__ float y1[C1_][16][24];   // stride 24 -> 2-way-max bank aliasing (free)
    const int b = blockIdx.x;
    const int t = threadIdx.x;

    // ---- load x[b] into LDS (coalesced) ----
    {
        const float* xb = x + (size_t)b * (CIN * 32 * 32);
        float* xsf = &xs[0][0][0];
        for (int i = t; i < CIN * 32 * 32; i += 256) xsf[i] = xb[i];
    }
    __syncthreads();

    // ---- LC + ReLU + maxpool2: thread owns pooled position (pi,pj), loops channels ----
    {
        const int pj = t & 15, pi = t >> 4;   // 16x16 pooled positions
        for (int o = 0; o < C1_; ++o) {
            float m = 0.f;  // relu(max(raw)) == max(relu(raw)); init 0 implements relu
            #pragma unroll
            for (int d = 0; d < 4; ++d) {
                const int i = 2 * pi + (d >> 1), j = 2 * pj + (d & 1);
                float acc = b_lc[(o * 32 + i) * 32 + j];
                const float* wp = w_lc + (size_t)o * (CIN * 9 * 1024) + i * 32 + j;
                #pragma unroll
                for (int c = 0; c < CIN; ++c) {
                    #pragma unroll
                    for (int k = 0; k < 9; ++k) {
                        const int ii = i + (k / 3) - 1;
                        const int jj = j + (k % 3) - 1;
                        const float xv =
                            ((unsigned)ii < 32u && (unsigned)jj < 32u) ? xs[c][ii][jj] : 0.f;
                        acc += xv * wp[(c * 9 + k) * 1024];
                    }
                }
                m = fmaxf(m, acc);
            }
            y1[o][pi][pj] = m;
        }
    }
    __syncthreads();

    // ---- conv3x3 SAME + bias + ReLU + maxpool2 ----
    // thread owns pooled position pos (8x8) for 16 output channels (og*16+u)
    {
        const int pos = t & 63, og = t >> 6;
        const int pr = pos >> 3, pc = pos & 7;
        float acc[16][4];
        #pragma unroll
        for (int u = 0; u < 16; ++u) {
            const float bv = b_conv[og * 16 + u];
            acc[u][0] = bv; acc[u][1] = bv; acc[u][2] = bv; acc[u][3] = bv;
        }
        for (int ic = 0; ic < C1_; ++ic) {
            // 4x4 input patch covering the 2x2 conv outputs of this pool quad
            float p[4][4];
            #pragma unroll
            for (int a = 0; a < 4; ++a) {
                const int ii = 2 * pr - 1 + a;
                const bool iok = (unsigned)ii < 16u;
                #pragma unroll
                for (int bb = 0; bb < 4; ++bb) {
                    const int jj = 2 * pc - 1 + bb;
                    p[a][bb] = (iok && (unsigned)jj < 16u) ? y1[ic][ii][jj] : 0.f;
                }
            }
            #pragma unroll
            for (int u = 0; u < 16; ++u) {
                const float* wp = w_conv + ((size_t)(og * 16 + u) * C1_ + ic) * 9;
                const float w0 = wp[0], w1 = wp[1], w2 = wp[2], w3 = wp[3], w4 = wp[4],
                            w5 = wp[5], w6 = wp[6], w7 = wp[7], w8 = wp[8];
                #pragma unroll
                for (int d = 0; d < 4; ++d) {
                    const int a0 = d >> 1, b0 = d & 1;
                    acc[u][d] += p[a0 + 0][b0 + 0] * w0 + p[a0 + 0][b0 + 1] * w1 +
                                 p[a0 + 0][b0 + 2] * w2 + p[a0 + 1][b0 + 0] * w3 +
                                 p[a0 + 1][b0 + 1] * w4 + p[a0 + 1][b0 + 2] * w5 +
                                 p[a0 + 2][b0 + 0] * w6 + p[a0 + 2][b0 + 1] * w7 +
                                 p[a0 + 2][b0 + 2] * w8;
                }
            }
        }
        float* outb = p2 + (size_t)b * 4096;
        #pragma unroll
        for (int u = 0; u < 16; ++u) {
            const int oc = og * 16 + u;
            float m = fmaxf(fmaxf(acc[u][0], acc[u][1]), fmaxf(acc[u][2], acc[u][3]));
            m = fmaxf(m, 0.f);
            outb[oc * 64 + pr * 8 + pc] = m;   // coalesced per wave
        }
    }
}

// ---------------------------------------------------------------------------
// FC1: out(4096,256) = relu(A(4096,4096) @ W(256,4096)^T + b)
// 64x64 tile per block, 4x4 per thread, BK=16
// ---------------------------------------------------------------------------
__global__ __launch_bounds__(256) void k_fc1(
    const float* __restrict__ A, const float* __restrict__ Wt,
    const float* __restrict__ bias, float* __restrict__ out)
{
    __shared__ float As[64][17];
    __shared__ float Bs[64][17];
    const int tx = threadIdx.x & 15, ty = threadIdx.x >> 4;
    const int m0 = blockIdx.x * 64, n0 = blockIdx.y * 64;
    const int lr = threadIdx.x >> 2;          // 0..63
    const int lk = (threadIdx.x & 3) * 4;     // 0,4,8,12
    float acc[4][4] = {};
    for (int k0 = 0; k0 < 4096; k0 += 16) {
        const float4 av = *(const float4*)(A  + (size_t)(m0 + lr) * 4096 + k0 + lk);
        const float4 bv = *(const float4*)(Wt + (size_t)(n0 + lr) * 4096 + k0 + lk);
        As[lr][lk + 0] = av.x; As[lr][lk + 1] = av.y; As[lr][lk + 2] = av.z; As[lr][lk + 3] = av.w;
        Bs[lr][lk + 0] = bv.x; Bs[lr][lk + 1] = bv.y; Bs[lr][lk + 2] = bv.z; Bs[lr][lk + 3] = bv.w;
        __syncthreads();
        #pragma unroll
        for (int kk = 0; kk < 16; ++kk) {
            float a[4], bb[4];
            #pragma unroll
            for (int i = 0; i < 4; ++i) a[i] = As[ty * 4 + i][kk];
            #pragma unroll
            for (int j = 0; j < 4; ++j) bb[j] = Bs[tx * 4 + j][kk];
            #pragma unroll
            for (int i = 0; i < 4; ++i)
                #pragma unroll
                for (int j = 0; j < 4; ++j) acc[i][j] += a[i] * bb[j];
        }
        __syncthreads();
    }
    #pragma unroll
    for (int i = 0; i < 4; ++i) {
        const int m = m0 + ty * 4 + i;
        #pragma unroll
        for (int j = 0; j < 4; ++j) {
            const int n = n0 + tx * 4 + j;
            out[(size_t)m * 256 + n] = fmaxf(acc[i][j] + bias[n], 0.f);
        }
    }
}

// ---------------------------------------------------------------------------
// FC2: out(4096,10) = fc1(4096,256) @ w_fc2(10,256)^T + b
// 320 threads = 32 rows x 10 cols, one full dot each
// ---------------------------------------------------------------------------
__global__ __launch_bounds__(320) void k_fc2(
    const float* __restrict__ fc1, const float* __restrict__ Wt,
    const float* __restrict__ bias, float* __restrict__ out)
{
    const int t = threadIdx.x;
    const int r = blockIdx.x * 32 + t / 10;
    const int n = t % 10;
    const float4* a = (const float4*)(fc1 + (size_t)r * 256);
    const float4* w = (const float4*)(Wt + (size_t)n * 256);
    float acc = bias[n];
    #pragma unroll 8
    for (int k = 0; k < 64; ++k) {
        const float4 av = a[k], wv = w[k];
        acc += av.x * wv.x + av.y * wv.y + av.z * wv.z + av.w * wv.w;
    }
    out[(size_t)r * 10 + n] = acc;
}

extern "C" void kernel_launch(void* const* d_in, const int* in_sizes, int n_in,
                              void* d_out, int out_size, void* d_ws, size_t ws_size,
                              hipStream_t stream)
{
    const float* x      = (const float*)d_in[0];
    const float* w_lc   = (const float*)d_in[1];
    const float* b_lc   = (const float*)d_in[2];
    const float* w_conv = (const float*)d_in[3];
    const float* b_conv = (const float*)d_in[4];
    const float* w_fc1  = (const float*)d_in[5];
    const float* b_fc1  = (const float*)d_in[6];
    const float* w_fc2  = (const float*)d_in[7];
    const float* b_fc2  = (const float*)d_in[8];
    float* out = (float*)d_out;

    float* p2  = (float*)d_ws;                    // (4096, 4096) fp32 = 67 MB
    float* fc1 = p2 + (size_t)4096 * 4096;        // (4096, 256) fp32 = 4.2 MB

    k_front<<<4096, 256, 0, stream>>>(x, w_lc, b_lc, w_conv, b_conv, p2);
    k_fc1<<<dim3(64, 4), 256, 0, stream>>>(p2, w_fc1, b_fc1, fc1);
    k_fc2<<<128, 320, 0, stream>>>(fc1, w_fc2, b_fc2, out);
}